// Round 1
// baseline (314.490 us; speedup 1.0000x reference)
//
#include <hip/hip_runtime.h>
#include <stdint.h>

typedef __bf16 bf16x8 __attribute__((ext_vector_type(8)));
typedef float f32x4 __attribute__((ext_vector_type(4)));
typedef unsigned short ushort_t;
typedef unsigned int uint_t;

__device__ inline ushort_t f2bf(float f) {
  uint_t u = __builtin_bit_cast(uint_t, f);
  u = (u + 0x7FFFu + ((u >> 16) & 1u)) >> 16;
  return (ushort_t)u;
}

// async global->LDS, 16B per lane. LDS dest must be wave-uniform base; HW adds lane*16.
__device__ inline void gll16(const void* g, void* l) {
  __builtin_amdgcn_global_load_lds(
      (__attribute__((address_space(1))) void*)(uintptr_t)g,
      (__attribute__((address_space(3))) void*)(uint32_t)(uintptr_t)l,
      16, 0, 0);
}

__global__ void cast_bf16(const float* __restrict__ in, ushort_t* __restrict__ out,
                          int n4, float scale) {
  int i = blockIdx.x * blockDim.x + threadIdx.x;
  int st = gridDim.x * blockDim.x;
  for (; i < n4; i += st) {
    float4 v = reinterpret_cast<const float4*>(in)[i];
    ushort4 o;
    o.x = f2bf(v.x * scale);
    o.y = f2bf(v.y * scale);
    o.z = f2bf(v.z * scale);
    o.w = f2bf(v.w * scale);
    reinterpret_cast<ushort4*>(out)[i] = o;
  }
}

// C[M,N] = A[M,K] * B[N,K]^T, bf16 in, fp32 accumulate. 128x128 tile, BK=32, 4 waves.
template <bool F32OUT>
__global__ __launch_bounds__(256) void gemm_bt(const ushort_t* __restrict__ A,
                                               const ushort_t* __restrict__ B,
                                               void* __restrict__ C, int M, int N, int K) {
  __shared__ __attribute__((aligned(16))) ushort_t As[128 * 32];
  __shared__ __attribute__((aligned(16))) ushort_t Bs[128 * 32];
  const int tid = threadIdx.x;
  const int lane = tid & 63;
  const int w = tid >> 6;
  const int wr = w >> 1, wc = w & 1;
  const int m0 = blockIdx.x * 128, n0 = blockIdx.y * 128;
  const int lr = lane & 15;
  const int lk = (lane >> 4) << 3;

  f32x4 acc[4][4] = {};

  const int srow = tid >> 2;
  const int scol = (tid & 3) << 3;
  const ushort_t* gA0 = A + (size_t)(m0 + srow) * K + scol;
  const ushort_t* gB0 = B + (size_t)(n0 + srow) * K + scol;
  const size_t rstep = (size_t)64 * K;
  ushort_t* lA0 = &As[(tid & 0xC0) * 8];
  ushort_t* lA1 = lA0 + 2048;
  ushort_t* lB0 = &Bs[(tid & 0xC0) * 8];
  ushort_t* lB1 = lB0 + 2048;

  for (int k0 = 0; k0 < K; k0 += 32) {
    gll16(gA0 + k0, lA0);
    gll16(gA0 + rstep + k0, lA1);
    gll16(gB0 + k0, lB0);
    gll16(gB0 + rstep + k0, lB1);
    __syncthreads();
    bf16x8 a[4], bb[4];
#pragma unroll
    for (int i = 0; i < 4; ++i)
      a[i] = *reinterpret_cast<const bf16x8*>(&As[(wr * 64 + i * 16 + lr) * 32 + lk]);
#pragma unroll
    for (int j = 0; j < 4; ++j)
      bb[j] = *reinterpret_cast<const bf16x8*>(&Bs[(wc * 64 + j * 16 + lr) * 32 + lk]);
#pragma unroll
    for (int i = 0; i < 4; ++i)
#pragma unroll
      for (int j = 0; j < 4; ++j)
        acc[i][j] = __builtin_amdgcn_mfma_f32_16x16x32_bf16(a[i], bb[j], acc[i][j], 0, 0, 0);
    __syncthreads();
  }

  const int orow = m0 + wr * 64 + ((lane >> 4) << 2);
  const int ocol = n0 + wc * 64 + lr;
#pragma unroll
  for (int i = 0; i < 4; ++i)
#pragma unroll
    for (int j = 0; j < 4; ++j)
#pragma unroll
      for (int r = 0; r < 4; ++r) {
        const size_t idx = (size_t)(orow + i * 16 + r) * N + (ocol + j * 16);
        if (F32OUT)
          ((float*)C)[idx] = acc[i][j][r];
        else
          ((ushort_t*)C)[idx] = f2bf(acc[i][j][r]);
      }
}

// Causal flash attention. QKV [8192,3072] bf16 (Q|K|V), Q pre-scaled by 0.125.
__global__ __launch_bounds__(256) void attn_fwd(const ushort_t* __restrict__ QKV,
                                                ushort_t* __restrict__ ctx) {
  const int bid = blockIdx.x;
  const int qt = bid & 15;
  const int h = (bid >> 4) & 15;
  const int b = bid >> 8;
  const int q0 = qt << 6;
  const int tid = threadIdx.x;
  const int lane = tid & 63;
  const int w = tid >> 6;
  const int lr = lane & 15;
  const int lg = lane >> 4;
  const int dk = lg << 3;

  __shared__ __attribute__((aligned(16))) ushort_t Ks[32 * 72];
  __shared__ __attribute__((aligned(16))) ushort_t Vt[64 * 40];
  __shared__ __attribute__((aligned(16))) ushort_t Pl[4][16 * 40];

  const size_t rowQ = (size_t)(b * 1024 + q0 + w * 16 + lr);
  const ushort_t* qp = QKV + rowQ * 3072 + h * 64 + dk;
  const bf16x8 qf0 = *reinterpret_cast<const bf16x8*>(qp);
  const bf16x8 qf1 = *reinterpret_cast<const bf16x8*>(qp + 32);

  f32x4 o[4] = {};
  float mrow[4], lrow[4];
#pragma unroll
  for (int r = 0; r < 4; ++r) {
    mrow[r] = -1e30f;
    lrow[r] = 0.f;
  }

  const int skey = tid >> 3;
  const int scg = tid & 7;
  const ushort_t* kgp = QKV + (size_t)(b * 1024 + skey) * 3072 + 1024 + h * 64 + scg * 8;
  const ushort_t* vgp = kgp + 1024;
  const int ntiles = (q0 >> 5) + 2;
  const int wqmax = q0 + w * 16 + 15;

  for (int t = 0; t < ntiles; ++t) {
    const int kb = t << 5;
    __syncthreads();
    *reinterpret_cast<uint4*>(&Ks[skey * 72 + scg * 8]) =
        *reinterpret_cast<const uint4*>(kgp + (size_t)kb * 3072);
    {
      ushort_t vv[8];
      *reinterpret_cast<uint4*>(vv) = *reinterpret_cast<const uint4*>(vgp + (size_t)kb * 3072);
#pragma unroll
      for (int j = 0; j < 8; ++j) Vt[(scg * 8 + j) * 40 + skey] = vv[j];
    }
    __syncthreads();
    if (kb > wqmax) continue;

    f32x4 s0 = {}, s1 = {};
    {
      const bf16x8 k00 = *reinterpret_cast<const bf16x8*>(&Ks[lr * 72 + dk]);
      const bf16x8 k01 = *reinterpret_cast<const bf16x8*>(&Ks[lr * 72 + 32 + dk]);
      const bf16x8 k10 = *reinterpret_cast<const bf16x8*>(&Ks[(16 + lr) * 72 + dk]);
      const bf16x8 k11 = *reinterpret_cast<const bf16x8*>(&Ks[(16 + lr) * 72 + 32 + dk]);
      s0 = __builtin_amdgcn_mfma_f32_16x16x32_bf16(qf0, k00, s0, 0, 0, 0);
      s0 = __builtin_amdgcn_mfma_f32_16x16x32_bf16(qf1, k01, s0, 0, 0, 0);
      s1 = __builtin_amdgcn_mfma_f32_16x16x32_bf16(qf0, k10, s1, 0, 0, 0);
      s1 = __builtin_amdgcn_mfma_f32_16x16x32_bf16(qf1, k11, s1, 0, 0, 0);
    }

    const int qrbase = q0 + w * 16 + lg * 4;
#pragma unroll
    for (int r = 0; r < 4; ++r) {
      const int qr = qrbase + r;
      float a0 = (kb + lr <= qr) ? s0[r] : -1e30f;
      float a1 = (kb + 16 + lr <= qr) ? s1[r] : -1e30f;
      float mx = fmaxf(a0, a1);
#pragma unroll
      for (int d = 1; d < 16; d <<= 1) mx = fmaxf(mx, __shfl_xor(mx, d));
      const float mnew = fmaxf(mrow[r], mx);
      const float p0 = __expf(a0 - mnew);
      const float p1 = __expf(a1 - mnew);
      float rs = p0 + p1;
#pragma unroll
      for (int d = 1; d < 16; d <<= 1) rs += __shfl_xor(rs, d);
      const float corr = __expf(mrow[r] - mnew);
      mrow[r] = mnew;
      lrow[r] = lrow[r] * corr + rs;
#pragma unroll
      for (int fh = 0; fh < 4; ++fh) o[fh][r] *= corr;
      Pl[w][(lg * 4 + r) * 40 + lr] = f2bf(p0);
      Pl[w][(lg * 4 + r) * 40 + 16 + lr] = f2bf(p1);
    }

    const bf16x8 pa = *reinterpret_cast<const bf16x8*>(&Pl[w][lr * 40 + dk]);
#pragma unroll
    for (int fh = 0; fh < 4; ++fh) {
      const bf16x8 vb = *reinterpret_cast<const bf16x8*>(&Vt[(fh * 16 + lr) * 40 + dk]);
      o[fh] = __builtin_amdgcn_mfma_f32_16x16x32_bf16(pa, vb, o[fh], 0, 0, 0);
    }
  }

  const size_t crow = (size_t)(b * 1024 + q0 + w * 16 + lg * 4);
#pragma unroll
  for (int fh = 0; fh < 4; ++fh)
#pragma unroll
    for (int r = 0; r < 4; ++r) {
      const float v = o[fh][r] / lrow[r];
      ctx[(crow + r) * 1024 + h * 64 + fh * 16 + lr] = f2bf(v);
    }
}

extern "C" void kernel_launch(void* const* d_in, const int* in_sizes, int n_in,
                              void* d_out, int out_size, void* d_ws, size_t ws_size,
                              hipStream_t stream) {
  const float* x = (const float*)d_in[0];
  const float* Wk = (const float*)d_in[1];
  const float* Wq = (const float*)d_in[2];
  const float* Wv = (const float*)d_in[3];
  const float* Wo = (const float*)d_in[4];

  char* ws = (char*)d_ws;
  ushort_t* xb = (ushort_t*)ws;                   // [8192,1024] bf16 (reused as ctx)
  ushort_t* Wc = (ushort_t*)(ws + (16u << 20));   // [3072,1024] bf16: Wq*0.125 | Wk | Wv
  ushort_t* Wob = (ushort_t*)(ws + (22u << 20));  // [1024,1024] bf16
  ushort_t* QKV = (ushort_t*)(ws + (24u << 20));  // [8192,3072] bf16
  ushort_t* ctx = xb;

  cast_bf16<<<2048, 256, 0, stream>>>(x, xb, (8192 * 1024) / 4, 1.0f);
  cast_bf16<<<512, 256, 0, stream>>>(Wq, Wc, (1024 * 1024) / 4, 0.125f);
  cast_bf16<<<512, 256, 0, stream>>>(Wk, Wc + 1024 * 1024, (1024 * 1024) / 4, 1.0f);
  cast_bf16<<<512, 256, 0, stream>>>(Wv, Wc + 2 * 1024 * 1024, (1024 * 1024) / 4, 1.0f);
  cast_bf16<<<512, 256, 0, stream>>>(Wo, Wob, (1024 * 1024) / 4, 1.0f);

  dim3 g1(64, 24);
  gemm_bt<false><<<g1, 256, 0, stream>>>(xb, Wc, QKV, 8192, 3072, 1024);

  attn_fwd<<<2048, 256, 0, stream>>>(QKV, ctx);

  dim3 g2(64, 8);
  gemm_bt<true><<<g2, 256, 0, stream>>>(ctx, Wob, (float*)d_out, 8192, 1024, 1024);
}

// Round 2
// 189.113 us; speedup vs baseline: 1.6630x; 1.6630x over previous
//
#include <hip/hip_runtime.h>
#include <stdint.h>

typedef __bf16 bf16x8 __attribute__((ext_vector_type(8)));
typedef float f32x4 __attribute__((ext_vector_type(4)));
typedef unsigned short ushort_t;
typedef unsigned int uint_t;

__device__ inline ushort_t f2bf(float f) {
  uint_t u = __builtin_bit_cast(uint_t, f);
  u = (u + 0x7FFFu + ((u >> 16) & 1u)) >> 16;
  return (ushort_t)u;
}

// async global->LDS, 16B per lane. LDS dest must be wave-uniform base; HW adds lane*16.
__device__ inline void gll16(const void* g, void* l) {
  __builtin_amdgcn_global_load_lds(
      (__attribute__((address_space(1))) void*)(uintptr_t)g,
      (__attribute__((address_space(3))) void*)(uint32_t)(uintptr_t)l,
      16, 0, 0);
}

__global__ void cast_bf16(const float* __restrict__ in, ushort_t* __restrict__ out,
                          int n4, float scale) {
  int i = blockIdx.x * blockDim.x + threadIdx.x;
  int st = gridDim.x * blockDim.x;
  for (; i < n4; i += st) {
    float4 v = reinterpret_cast<const float4*>(in)[i];
    ushort4 o;
    o.x = f2bf(v.x * scale);
    o.y = f2bf(v.y * scale);
    o.z = f2bf(v.z * scale);
    o.w = f2bf(v.w * scale);
    reinterpret_cast<ushort4*>(out)[i] = o;
  }
}

// C[M,N] = A[M,K] * B[N,K]^T, bf16 in, fp32 accumulate. 128x128 tile, BK=32, 4 waves.
template <bool F32OUT>
__global__ __launch_bounds__(256) void gemm_bt(const ushort_t* __restrict__ A,
                                               const ushort_t* __restrict__ B,
                                               void* __restrict__ C, int M, int N, int K) {
  __shared__ __attribute__((aligned(16))) ushort_t As[128 * 32];
  __shared__ __attribute__((aligned(16))) ushort_t Bs[128 * 32];
  const int tid = threadIdx.x;
  const int lane = tid & 63;
  const int w = tid >> 6;
  const int wr = w >> 1, wc = w & 1;
  const int m0 = blockIdx.x * 128, n0 = blockIdx.y * 128;
  const int lr = lane & 15;
  const int lk = (lane >> 4) << 3;

  f32x4 acc[4][4] = {};

  const int srow = tid >> 2;
  const int scol = (tid & 3) << 3;
  const ushort_t* gA0 = A + (size_t)(m0 + srow) * K + scol;
  const ushort_t* gB0 = B + (size_t)(n0 + srow) * K + scol;
  const size_t rstep = (size_t)64 * K;
  ushort_t* lA0 = &As[(tid & 0xC0) * 8];
  ushort_t* lA1 = lA0 + 2048;
  ushort_t* lB0 = &Bs[(tid & 0xC0) * 8];
  ushort_t* lB1 = lB0 + 2048;

  for (int k0 = 0; k0 < K; k0 += 32) {
    gll16(gA0 + k0, lA0);
    gll16(gA0 + rstep + k0, lA1);
    gll16(gB0 + k0, lB0);
    gll16(gB0 + rstep + k0, lB1);
    __syncthreads();
    bf16x8 a[4], bb[4];
#pragma unroll
    for (int i = 0; i < 4; ++i)
      a[i] = *reinterpret_cast<const bf16x8*>(&As[(wr * 64 + i * 16 + lr) * 32 + lk]);
#pragma unroll
    for (int j = 0; j < 4; ++j)
      bb[j] = *reinterpret_cast<const bf16x8*>(&Bs[(wc * 64 + j * 16 + lr) * 32 + lk]);
#pragma unroll
    for (int i = 0; i < 4; ++i)
#pragma unroll
      for (int j = 0; j < 4; ++j)
        acc[i][j] = __builtin_amdgcn_mfma_f32_16x16x32_bf16(a[i], bb[j], acc[i][j], 0, 0, 0);
    __syncthreads();
  }

  const int orow = m0 + wr * 64 + ((lane >> 4) << 2);
  const int ocol = n0 + wc * 64 + lr;
#pragma unroll
  for (int i = 0; i < 4; ++i)
#pragma unroll
    for (int j = 0; j < 4; ++j)
#pragma unroll
      for (int r = 0; r < 4; ++r) {
        const size_t idx = (size_t)(orow + i * 16 + r) * N + (ocol + j * 16);
        if (F32OUT)
          ((float*)C)[idx] = acc[i][j][r];
        else
          ((ushort_t*)C)[idx] = f2bf(acc[i][j][r]);
      }
}

// Causal flash attention. QKV [8192,3072] bf16 (Q|K|V), Q pre-scaled by 0.125.
// Block = (b, h, pair p): processes q-tile qt=p then qt=15-p (uniform 17 KV-tiles).
// 4 waves x 16 q-rows; KVBLK=64; reg-staged K/V with conflict-free LDS layouts.
__global__ __launch_bounds__(256, 4) void attn_fwd(const ushort_t* __restrict__ QKV,
                                                   ushort_t* __restrict__ ctx) {
  const int bid = blockIdx.x;
  const int h = bid & 15;          // fast: blocks sharing (b,h) are 128 apart -> same XCD
  const int b = (bid >> 4) & 7;
  const int p = bid >> 7;          // 0..7
  const int tid = threadIdx.x;
  const int lane = tid & 63;
  const int w = tid >> 6;
  const int lr = lane & 15;
  const int lg = lane >> 4;
  const int dk = lg << 3;

  __shared__ __attribute__((aligned(16))) ushort_t Ks[64 * 72];  // [key][d], stride 72 u16 = 36 dw
  __shared__ __attribute__((aligned(16))) uint_t VtDw[64 * 36];  // [d][key-pair dword], stride 36 dw
  __shared__ __attribute__((aligned(16))) ushort_t Pl[4][16 * 72];

  // staging thread maps
  const int kkey = tid >> 2, kdg = tid & 3;   // K: row kkey, d-chunk kdg*16
  const int vkp = tid & 31, vdg = tid >> 5;   // V: rows 2vkp,2vkp+1, d-chunk vdg*8
  const ushort_t* kgbase =
      QKV + ((size_t)(b * 1024 + kkey)) * 3072 + 1024 + h * 64 + kdg * 16;
  const ushort_t* vgbase =
      QKV + ((size_t)(b * 1024 + 2 * vkp)) * 3072 + 2048 + h * 64 + vdg * 8;

  for (int pi = 0; pi < 2; ++pi) {
    const int qt = pi ? (15 - p) : p;
    const int q0 = qt << 6;
    const int nt = qt + 1;

    const ushort_t* qp =
        QKV + ((size_t)(b * 1024 + q0 + w * 16 + lr)) * 3072 + h * 64 + dk;
    const bf16x8 qf0 = *reinterpret_cast<const bf16x8*>(qp);
    const bf16x8 qf1 = *reinterpret_cast<const bf16x8*>(qp + 32);

    f32x4 o[4] = {};
    float mrow[4], lrow[4];
#pragma unroll
    for (int r = 0; r < 4; ++r) {
      mrow[r] = -1e30f;
      lrow[r] = 0.f;
    }

    uint4 rk0 = *reinterpret_cast<const uint4*>(kgbase);
    uint4 rk1 = *reinterpret_cast<const uint4*>(kgbase + 8);
    uint4 rv0 = *reinterpret_cast<const uint4*>(vgbase);
    uint4 rv1 = *reinterpret_cast<const uint4*>(vgbase + 3072);

    for (int t = 0; t < nt; ++t) {
      __syncthreads();  // prior tile's LDS consumers done
      {
        uint_t* kd = reinterpret_cast<uint_t*>(&Ks[kkey * 72 + kdg * 16]);
        *reinterpret_cast<uint4*>(kd) = rk0;
        *reinterpret_cast<uint4*>(kd + 4) = rk1;
        const ushort_t* e0 = reinterpret_cast<const ushort_t*>(&rv0);
        const ushort_t* e1 = reinterpret_cast<const ushort_t*>(&rv1);
#pragma unroll
        for (int j = 0; j < 8; ++j)
          VtDw[(vdg * 8 + j) * 36 + vkp] = (uint_t)e0[j] | ((uint_t)e1[j] << 16);
      }
      __syncthreads();

      if (t + 1 < nt) {  // prefetch next tile; latency hides under compute
        const size_t off = (size_t)(t + 1) * 64 * 3072;
        rk0 = *reinterpret_cast<const uint4*>(kgbase + off);
        rk1 = *reinterpret_cast<const uint4*>(kgbase + off + 8);
        rv0 = *reinterpret_cast<const uint4*>(vgbase + off);
        rv1 = *reinterpret_cast<const uint4*>(vgbase + off + 3072);
      }

      const int kb = t << 6;
      // ---- QK^T: 4 key-frags x 2 d-blocks
      f32x4 s0 = {}, s1 = {}, s2 = {}, s3 = {};
      {
        const bf16x8 k00 = *reinterpret_cast<const bf16x8*>(&Ks[lr * 72 + dk]);
        const bf16x8 k01 = *reinterpret_cast<const bf16x8*>(&Ks[lr * 72 + 32 + dk]);
        const bf16x8 k10 = *reinterpret_cast<const bf16x8*>(&Ks[(16 + lr) * 72 + dk]);
        const bf16x8 k11 = *reinterpret_cast<const bf16x8*>(&Ks[(16 + lr) * 72 + 32 + dk]);
        const bf16x8 k20 = *reinterpret_cast<const bf16x8*>(&Ks[(32 + lr) * 72 + dk]);
        const bf16x8 k21 = *reinterpret_cast<const bf16x8*>(&Ks[(32 + lr) * 72 + 32 + dk]);
        const bf16x8 k30 = *reinterpret_cast<const bf16x8*>(&Ks[(48 + lr) * 72 + dk]);
        const bf16x8 k31 = *reinterpret_cast<const bf16x8*>(&Ks[(48 + lr) * 72 + 32 + dk]);
        s0 = __builtin_amdgcn_mfma_f32_16x16x32_bf16(qf0, k00, s0, 0, 0, 0);
        s0 = __builtin_amdgcn_mfma_f32_16x16x32_bf16(qf1, k01, s0, 0, 0, 0);
        s1 = __builtin_amdgcn_mfma_f32_16x16x32_bf16(qf0, k10, s1, 0, 0, 0);
        s1 = __builtin_amdgcn_mfma_f32_16x16x32_bf16(qf1, k11, s1, 0, 0, 0);
        s2 = __builtin_amdgcn_mfma_f32_16x16x32_bf16(qf0, k20, s2, 0, 0, 0);
        s2 = __builtin_amdgcn_mfma_f32_16x16x32_bf16(qf1, k21, s2, 0, 0, 0);
        s3 = __builtin_amdgcn_mfma_f32_16x16x32_bf16(qf0, k30, s3, 0, 0, 0);
        s3 = __builtin_amdgcn_mfma_f32_16x16x32_bf16(qf1, k31, s3, 0, 0, 0);
      }

      // ---- online softmax (diagonal tile only needs masking)
      const bool dia = (t == nt - 1);
#pragma unroll
      for (int r = 0; r < 4; ++r) {
        float a0 = s0[r], a1 = s1[r], a2 = s2[r], a3 = s3[r];
        if (dia) {
          const int qr = q0 + w * 16 + lg * 4 + r;
          a0 = (kb + lr <= qr) ? a0 : -1e30f;
          a1 = (kb + 16 + lr <= qr) ? a1 : -1e30f;
          a2 = (kb + 32 + lr <= qr) ? a2 : -1e30f;
          a3 = (kb + 48 + lr <= qr) ? a3 : -1e30f;
        }
        float mx = fmaxf(fmaxf(a0, a1), fmaxf(a2, a3));
#pragma unroll
        for (int d = 1; d < 16; d <<= 1) mx = fmaxf(mx, __shfl_xor(mx, d));
        const float mnew = fmaxf(mrow[r], mx);
        const float p0 = __expf(a0 - mnew);
        const float p1 = __expf(a1 - mnew);
        const float p2 = __expf(a2 - mnew);
        const float p3 = __expf(a3 - mnew);
        float rs = (p0 + p1) + (p2 + p3);
#pragma unroll
        for (int d = 1; d < 16; d <<= 1) rs += __shfl_xor(rs, d);
        const float corr = __expf(mrow[r] - mnew);
        mrow[r] = mnew;
        lrow[r] = lrow[r] * corr + rs;
        o[0][r] *= corr;
        o[1][r] *= corr;
        o[2][r] *= corr;
        o[3][r] *= corr;
        ushort_t* pl = &Pl[w][(lg * 4 + r) * 72 + lr];
        pl[0] = f2bf(p0);
        pl[16] = f2bf(p1);
        pl[32] = f2bf(p2);
        pl[48] = f2bf(p3);
      }

      // ---- PV: A = P (from Pl), B = V^T (packed dwords)
#pragma unroll
      for (int kblk = 0; kblk < 2; ++kblk) {
        const bf16x8 pa =
            *reinterpret_cast<const bf16x8*>(&Pl[w][lr * 72 + kblk * 32 + dk]);
#pragma unroll
        for (int fh = 0; fh < 4; ++fh) {
          const bf16x8 vb = *reinterpret_cast<const bf16x8*>(
              &VtDw[(fh * 16 + lr) * 36 + kblk * 16 + lg * 4]);
          o[fh] = __builtin_amdgcn_mfma_f32_16x16x32_bf16(pa, vb, o[fh], 0, 0, 0);
        }
      }
    }

    const size_t crow = (size_t)(b * 1024 + q0 + w * 16 + lg * 4);
#pragma unroll
    for (int fh = 0; fh < 4; ++fh)
#pragma unroll
      for (int r = 0; r < 4; ++r) {
        const float v = o[fh][r] / lrow[r];
        ctx[(crow + r) * 1024 + h * 64 + fh * 16 + lr] = f2bf(v);
      }
  }
}

extern "C" void kernel_launch(void* const* d_in, const int* in_sizes, int n_in,
                              void* d_out, int out_size, void* d_ws, size_t ws_size,
                              hipStream_t stream) {
  const float* x = (const float*)d_in[0];
  const float* Wk = (const float*)d_in[1];
  const float* Wq = (const float*)d_in[2];
  const float* Wv = (const float*)d_in[3];
  const float* Wo = (const float*)d_in[4];

  char* ws = (char*)d_ws;
  ushort_t* xb = (ushort_t*)ws;                   // [8192,1024] bf16 (reused as ctx)
  ushort_t* Wc = (ushort_t*)(ws + (16u << 20));   // [3072,1024] bf16: Wq*0.125 | Wk | Wv
  ushort_t* Wob = (ushort_t*)(ws + (22u << 20));  // [1024,1024] bf16
  ushort_t* QKV = (ushort_t*)(ws + (24u << 20));  // [8192,3072] bf16
  ushort_t* ctx = xb;

  cast_bf16<<<2048, 256, 0, stream>>>(x, xb, (8192 * 1024) / 4, 1.0f);
  cast_bf16<<<512, 256, 0, stream>>>(Wq, Wc, (1024 * 1024) / 4, 0.125f);
  cast_bf16<<<512, 256, 0, stream>>>(Wk, Wc + 1024 * 1024, (1024 * 1024) / 4, 1.0f);
  cast_bf16<<<512, 256, 0, stream>>>(Wv, Wc + 2 * 1024 * 1024, (1024 * 1024) / 4, 1.0f);
  cast_bf16<<<512, 256, 0, stream>>>(Wo, Wob, (1024 * 1024) / 4, 1.0f);

  dim3 g1(64, 24);
  gemm_bt<false><<<g1, 256, 0, stream>>>(xb, Wc, QKV, 8192, 3072, 1024);

  attn_fwd<<<1024, 256, 0, stream>>>(QKV, ctx);

  dim3 g2(64, 8);
  gemm_bt<true><<<g2, 256, 0, stream>>>(ctx, Wob, (float*)d_out, 8192, 1024, 1024);
}

// Round 3
// 156.650 us; speedup vs baseline: 2.0076x; 1.2072x over previous
//
#include <hip/hip_runtime.h>
#include <stdint.h>

typedef __bf16 bf16x8 __attribute__((ext_vector_type(8)));
typedef float f32x4 __attribute__((ext_vector_type(4)));
typedef unsigned short ushort_t;
typedef unsigned int uint_t;

__device__ inline ushort_t f2bf(float f) {
  uint_t u = __builtin_bit_cast(uint_t, f);
  u = (u + 0x7FFFu + ((u >> 16) & 1u)) >> 16;
  return (ushort_t)u;
}

// async global->LDS, 16B per lane. LDS dest must be wave-uniform base; HW adds lane*16.
__device__ inline void gll16(const void* g, void* l) {
  __builtin_amdgcn_global_load_lds(
      (__attribute__((address_space(1))) void*)(uintptr_t)g,
      (__attribute__((address_space(3))) void*)(uint32_t)(uintptr_t)l,
      16, 0, 0);
}

__global__ void cast_bf16(const float* __restrict__ in, ushort_t* __restrict__ out,
                          int n4, float scale) {
  int i = blockIdx.x * blockDim.x + threadIdx.x;
  int st = gridDim.x * blockDim.x;
  for (; i < n4; i += st) {
    float4 v = reinterpret_cast<const float4*>(in)[i];
    ushort4 o;
    o.x = f2bf(v.x * scale);
    o.y = f2bf(v.y * scale);
    o.z = f2bf(v.z * scale);
    o.w = f2bf(v.w * scale);
    reinterpret_cast<ushort4*>(out)[i] = o;
  }
}

// All 4 weight matrices in one launch; out = Wq*s | Wk | Wv | Wo contiguous.
__global__ void cast_w4(const float* __restrict__ w0, const float* __restrict__ w1,
                        const float* __restrict__ w2, const float* __restrict__ w3,
                        ushort_t* __restrict__ out, float s0) {
  const int i = blockIdx.x * 256 + threadIdx.x;  // 0 .. 4*262144-1 float4 units
  const int which = i >> 18;
  const float* src = which == 0 ? w0 : which == 1 ? w1 : which == 2 ? w2 : w3;
  const float sc = which == 0 ? s0 : 1.0f;
  float4 v = reinterpret_cast<const float4*>(src)[i & 0x3FFFF];
  ushort4 o;
  o.x = f2bf(v.x * sc);
  o.y = f2bf(v.y * sc);
  o.z = f2bf(v.z * sc);
  o.w = f2bf(v.w * sc);
  reinterpret_cast<ushort4*>(out)[i] = o;
}

// C[M,N] = A[M,K] * B[N,K]^T, bf16 in, fp32 accumulate. 128x128 tile, BK=32, 4 waves.
template <bool F32OUT>
__global__ __launch_bounds__(256) void gemm_bt(const ushort_t* __restrict__ A,
                                               const ushort_t* __restrict__ B,
                                               void* __restrict__ C, int M, int N, int K) {
  __shared__ __attribute__((aligned(16))) ushort_t As[128 * 32];
  __shared__ __attribute__((aligned(16))) ushort_t Bs[128 * 32];
  const int tid = threadIdx.x;
  const int lane = tid & 63;
  const int w = tid >> 6;
  const int wr = w >> 1, wc = w & 1;
  const int m0 = blockIdx.x * 128, n0 = blockIdx.y * 128;
  const int lr = lane & 15;
  const int lk = (lane >> 4) << 3;

  f32x4 acc[4][4] = {};

  const int srow = tid >> 2;
  const int scol = (tid & 3) << 3;
  const ushort_t* gA0 = A + (size_t)(m0 + srow) * K + scol;
  const ushort_t* gB0 = B + (size_t)(n0 + srow) * K + scol;
  const size_t rstep = (size_t)64 * K;
  ushort_t* lA0 = &As[(tid & 0xC0) * 8];
  ushort_t* lA1 = lA0 + 2048;
  ushort_t* lB0 = &Bs[(tid & 0xC0) * 8];
  ushort_t* lB1 = lB0 + 2048;

  for (int k0 = 0; k0 < K; k0 += 32) {
    gll16(gA0 + k0, lA0);
    gll16(gA0 + rstep + k0, lA1);
    gll16(gB0 + k0, lB0);
    gll16(gB0 + rstep + k0, lB1);
    __syncthreads();
    bf16x8 a[4], bb[4];
#pragma unroll
    for (int i = 0; i < 4; ++i)
      a[i] = *reinterpret_cast<const bf16x8*>(&As[(wr * 64 + i * 16 + lr) * 32 + lk]);
#pragma unroll
    for (int j = 0; j < 4; ++j)
      bb[j] = *reinterpret_cast<const bf16x8*>(&Bs[(wc * 64 + j * 16 + lr) * 32 + lk]);
#pragma unroll
    for (int i = 0; i < 4; ++i)
#pragma unroll
      for (int j = 0; j < 4; ++j)
        acc[i][j] = __builtin_amdgcn_mfma_f32_16x16x32_bf16(a[i], bb[j], acc[i][j], 0, 0, 0);
    __syncthreads();
  }

  const int orow = m0 + wr * 64 + ((lane >> 4) << 2);
  const int ocol = n0 + wc * 64 + lr;
#pragma unroll
  for (int i = 0; i < 4; ++i)
#pragma unroll
    for (int j = 0; j < 4; ++j)
#pragma unroll
      for (int r = 0; r < 4; ++r) {
        const size_t idx = (size_t)(orow + i * 16 + r) * N + (ocol + j * 16);
        if (F32OUT)
          ((float*)C)[idx] = acc[i][j][r];
        else
          ((ushort_t*)C)[idx] = f2bf(acc[i][j][r]);
      }
}

// Causal flash attention. QKV [8192,3072] bf16 (Q|K|V), Q pre-scaled by 0.125*log2(e).
// Block = (b,h,p): q-tiles qt=p then 7-p of 128 rows (uniform 18 KV-tiles/block).
// 4 waves x 32 q-rows; KVBLK=64. Swapped QK^T (mfma(K,Q)) -> lane-local softmax,
// fixed max (exp2(s - 16*log2e)), deferred row-sum reduction.
__global__ __launch_bounds__(256, 2) void attn_fwd(const ushort_t* __restrict__ QKV,
                                                   ushort_t* __restrict__ ctx) {
  const int bid = blockIdx.x;
  const int h = bid & 15;  // blocks sharing (b,h) are 128 apart -> same XCD
  const int b = (bid >> 4) & 7;
  const int p = bid >> 7;  // 0..3
  const int tid = threadIdx.x;
  const int lane = tid & 63;
  const int w = tid >> 6;
  const int lr = lane & 15;
  const int lg = lane >> 4;
  const int dk = lg << 3;

  __shared__ __attribute__((aligned(16))) ushort_t Ks[64 * 72];   // [key][d]
  __shared__ __attribute__((aligned(16))) uint_t VtDw[64 * 36];   // [d][key-pair dw]
  __shared__ __attribute__((aligned(16))) ushort_t Pl[4][32 * 72];

  const int kkey = tid >> 2, kdg = tid & 3;
  const int vkp = tid & 31, vdg = tid >> 5;
  const ushort_t* kgbase =
      QKV + ((size_t)(b * 1024 + kkey)) * 3072 + 1024 + h * 64 + kdg * 16;
  const ushort_t* vgbase =
      QKV + ((size_t)(b * 1024 + 2 * vkp)) * 3072 + 2048 + h * 64 + vdg * 8;

  const float FMAX2 = 23.083120654223414f;  // 16 * log2(e)

  for (int pi = 0; pi < 2; ++pi) {
    const int qt = pi ? (7 - p) : p;
    const int q0 = qt << 7;
    const int nt = (qt + 1) << 1;
    const int wrow0 = q0 + w * 32;

    bf16x8 qf[2][2];
#pragma unroll
    for (int i = 0; i < 2; ++i) {
      const ushort_t* qp =
          QKV + ((size_t)(b * 1024 + wrow0 + i * 16 + lr)) * 3072 + h * 64 + dk;
      qf[i][0] = *reinterpret_cast<const bf16x8*>(qp);
      qf[i][1] = *reinterpret_cast<const bf16x8*>(qp + 32);
    }

    f32x4 o[2][4] = {};
    float lsum[2] = {0.f, 0.f};

    uint4 rk0 = *reinterpret_cast<const uint4*>(kgbase);
    uint4 rk1 = *reinterpret_cast<const uint4*>(kgbase + 8);
    uint4 rv0 = *reinterpret_cast<const uint4*>(vgbase);
    uint4 rv1 = *reinterpret_cast<const uint4*>(vgbase + 3072);

    for (int t = 0; t < nt; ++t) {
      __syncthreads();
      {
        uint_t* kd = reinterpret_cast<uint_t*>(&Ks[kkey * 72 + kdg * 16]);
        *reinterpret_cast<uint4*>(kd) = rk0;
        *reinterpret_cast<uint4*>(kd + 4) = rk1;
        const ushort_t* e0 = reinterpret_cast<const ushort_t*>(&rv0);
        const ushort_t* e1 = reinterpret_cast<const ushort_t*>(&rv1);
#pragma unroll
        for (int j = 0; j < 8; ++j)
          VtDw[(vdg * 8 + j) * 36 + vkp] = (uint_t)e0[j] | ((uint_t)e1[j] << 16);
      }
      __syncthreads();

      if (t + 1 < nt) {
        const size_t off = (size_t)(t + 1) * 64 * 3072;
        rk0 = *reinterpret_cast<const uint4*>(kgbase + off);
        rk1 = *reinterpret_cast<const uint4*>(kgbase + off + 8);
        rv0 = *reinterpret_cast<const uint4*>(vgbase + off);
        rv1 = *reinterpret_cast<const uint4*>(vgbase + off + 3072);
      }

      const int kb = t << 6;
      if (kb > wrow0 + 31) continue;  // fully masked for this wave (uniform)

      // ---- QK^T swapped: S^T frag, lane holds keys kb+f*16+lg*4+r for q-row lr
      bf16x8 kf0[4], kf1[4];
#pragma unroll
      for (int f = 0; f < 4; ++f) {
        kf0[f] = *reinterpret_cast<const bf16x8*>(&Ks[(f * 16 + lr) * 72 + dk]);
        kf1[f] = *reinterpret_cast<const bf16x8*>(&Ks[(f * 16 + lr) * 72 + 32 + dk]);
      }
      f32x4 s[2][4];
#pragma unroll
      for (int i = 0; i < 2; ++i)
#pragma unroll
        for (int f = 0; f < 4; ++f) {
          f32x4 z = {0.f, 0.f, 0.f, 0.f};
          z = __builtin_amdgcn_mfma_f32_16x16x32_bf16(kf0[f], qf[i][0], z, 0, 0, 0);
          s[i][f] = __builtin_amdgcn_mfma_f32_16x16x32_bf16(kf1[f], qf[i][1], z, 0, 0, 0);
        }

      const bool needmask = (kb + 63 > wrow0);
#pragma unroll
      for (int i = 0; i < 2; ++i) {
        const int qr = wrow0 + i * 16 + lr;
#pragma unroll
        for (int f = 0; f < 4; ++f) {
          const int kbase = kb + f * 16 + (lg << 2);
          float p0 = __builtin_amdgcn_exp2f(s[i][f][0] - FMAX2);
          float p1 = __builtin_amdgcn_exp2f(s[i][f][1] - FMAX2);
          float p2 = __builtin_amdgcn_exp2f(s[i][f][2] - FMAX2);
          float p3 = __builtin_amdgcn_exp2f(s[i][f][3] - FMAX2);
          if (needmask) {
            p0 = (kbase + 0 <= qr) ? p0 : 0.f;
            p1 = (kbase + 1 <= qr) ? p1 : 0.f;
            p2 = (kbase + 2 <= qr) ? p2 : 0.f;
            p3 = (kbase + 3 <= qr) ? p3 : 0.f;
          }
          lsum[i] += (p0 + p1) + (p2 + p3);
          ushort4 pk = {f2bf(p0), f2bf(p1), f2bf(p2), f2bf(p3)};
          *reinterpret_cast<ushort4*>(
              &Pl[w][(i * 16 + lr) * 72 + f * 16 + (lg << 2)]) = pk;
        }
      }

      // ---- PV: vb loaded once, reused by both row-frags
      bf16x8 vb[2][4];
#pragma unroll
      for (int kblk = 0; kblk < 2; ++kblk)
#pragma unroll
        for (int fh = 0; fh < 4; ++fh)
          vb[kblk][fh] = *reinterpret_cast<const bf16x8*>(
              &VtDw[(fh * 16 + lr) * 36 + kblk * 16 + (lg << 2)]);
#pragma unroll
      for (int i = 0; i < 2; ++i)
#pragma unroll
        for (int kblk = 0; kblk < 2; ++kblk) {
          const bf16x8 pa = *reinterpret_cast<const bf16x8*>(
              &Pl[w][(i * 16 + lr) * 72 + kblk * 32 + dk]);
#pragma unroll
          for (int fh = 0; fh < 4; ++fh)
            o[i][fh] = __builtin_amdgcn_mfma_f32_16x16x32_bf16(pa, vb[kblk][fh],
                                                               o[i][fh], 0, 0, 0);
        }
    }

    // ---- finalize: row-sum lives at lane lr per frag; broadcast to C layout
#pragma unroll
    for (int i = 0; i < 2; ++i) {
      float ls = lsum[i];
      ls += __shfl_xor(ls, 16);
      ls += __shfl_xor(ls, 32);
      const float linv = 1.0f / ls;
      const size_t crow = (size_t)(b * 1024 + wrow0 + i * 16 + (lg << 2));
#pragma unroll
      for (int r = 0; r < 4; ++r) {
        const float li = __shfl(linv, (lg << 2) + r);
#pragma unroll
        for (int fh = 0; fh < 4; ++fh)
          ctx[(crow + r) * 1024 + h * 64 + fh * 16 + lr] = f2bf(o[i][fh][r] * li);
      }
    }
  }
}

extern "C" void kernel_launch(void* const* d_in, const int* in_sizes, int n_in,
                              void* d_out, int out_size, void* d_ws, size_t ws_size,
                              hipStream_t stream) {
  const float* x = (const float*)d_in[0];
  const float* Wk = (const float*)d_in[1];
  const float* Wq = (const float*)d_in[2];
  const float* Wv = (const float*)d_in[3];
  const float* Wo = (const float*)d_in[4];

  char* ws = (char*)d_ws;
  ushort_t* xb = (ushort_t*)ws;                  // [8192,1024] bf16 (reused as ctx)
  ushort_t* Wc = (ushort_t*)(ws + (16u << 20));  // Wq*0.125*log2e | Wk | Wv | Wo
  ushort_t* Wob = Wc + 3u * 1024 * 1024;
  ushort_t* QKV = (ushort_t*)(ws + (24u << 20));  // [8192,3072] bf16
  ushort_t* ctx = xb;

  cast_bf16<<<2048, 256, 0, stream>>>(x, xb, (8192 * 1024) / 4, 1.0f);
  cast_w4<<<4096, 256, 0, stream>>>(Wq, Wk, Wv, Wo, Wc, 0.125f * 1.4426950408889634f);

  dim3 g1(64, 24);
  gemm_bt<false><<<g1, 256, 0, stream>>>(xb, Wc, QKV, 8192, 3072, 1024);

  attn_fwd<<<512, 256, 0, stream>>>(QKV, ctx);

  dim3 g2(64, 8);
  gemm_bt<true><<<g2, 256, 0, stream>>>(ctx, Wob, (float*)d_out, 8192, 1024, 1024);
}

// Round 4
// 147.406 us; speedup vs baseline: 2.1335x; 1.0627x over previous
//
#include <hip/hip_runtime.h>
#include <stdint.h>

typedef __bf16 bf16x8 __attribute__((ext_vector_type(8)));
typedef float f32x4 __attribute__((ext_vector_type(4)));
typedef unsigned short ushort_t;
typedef unsigned int uint_t;

__device__ inline ushort_t f2bf(float f) {
  uint_t u = __builtin_bit_cast(uint_t, f);
  u = (u + 0x7FFFu + ((u >> 16) & 1u)) >> 16;
  return (ushort_t)u;
}

// async global->LDS, 16B per lane. LDS dest must be wave-uniform base; HW adds lane*16.
__device__ inline void gll16(const void* g, void* l) {
  __builtin_amdgcn_global_load_lds(
      (__attribute__((address_space(1))) void*)(uintptr_t)g,
      (__attribute__((address_space(3))) void*)(uint32_t)(uintptr_t)l,
      16, 0, 0);
}

__global__ void cast_bf16(const float* __restrict__ in, ushort_t* __restrict__ out,
                          int n4, float scale) {
  int i = blockIdx.x * blockDim.x + threadIdx.x;
  int st = gridDim.x * blockDim.x;
  for (; i < n4; i += st) {
    float4 v = reinterpret_cast<const float4*>(in)[i];
    ushort4 o;
    o.x = f2bf(v.x * scale);
    o.y = f2bf(v.y * scale);
    o.z = f2bf(v.z * scale);
    o.w = f2bf(v.w * scale);
    reinterpret_cast<ushort4*>(out)[i] = o;
  }
}

// All 4 weight matrices in one launch; out = Wq*s | Wk | Wv | Wo contiguous.
__global__ void cast_w4(const float* __restrict__ w0, const float* __restrict__ w1,
                        const float* __restrict__ w2, const float* __restrict__ w3,
                        ushort_t* __restrict__ out, float s0) {
  const int i = blockIdx.x * 256 + threadIdx.x;
  const int which = i >> 18;
  const float* src = which == 0 ? w0 : which == 1 ? w1 : which == 2 ? w2 : w3;
  const float sc = which == 0 ? s0 : 1.0f;
  float4 v = reinterpret_cast<const float4*>(src)[i & 0x3FFFF];
  ushort4 o;
  o.x = f2bf(v.x * sc);
  o.y = f2bf(v.y * sc);
  o.z = f2bf(v.z * sc);
  o.w = f2bf(v.w * sc);
  reinterpret_cast<ushort4*>(out)[i] = o;
}

// ---------------- 8-phase 256x256 GEMM: C[8192,3072] = A[8192,1024] * B[3072,1024]^T
#define MFMA16(A_, B_, C_) __builtin_amdgcn_mfma_f32_16x16x32_bf16(A_, B_, C_, 0, 0, 0)

// stage one operand tile half-pair: 4 gll16 (rows +0,+64,+128,+192), LDS linear.
#define STAGE_A(WBU, SK)                                              \
  gll16(gA + (SK), &smem[(WBU) + (w << 9)]);                          \
  gll16(gA + 65536 + (SK), &smem[(WBU) + 4096 + (w << 9)]);           \
  gll16(gA + 131072 + (SK), &smem[(WBU) + 8192 + (w << 9)]);          \
  gll16(gA + 196608 + (SK), &smem[(WBU) + 12288 + (w << 9)]);
#define STAGE_B(WBU, SK)                                              \
  gll16(gB + (SK), &smem[(WBU) + 16384 + (w << 9)]);                  \
  gll16(gB + 65536 + (SK), &smem[(WBU) + 20480 + (w << 9)]);          \
  gll16(gB + 131072 + (SK), &smem[(WBU) + 24576 + (w << 9)]);         \
  gll16(gB + 196608 + (SK), &smem[(WBU) + 28672 + (w << 9)]);

#define RD_A(RBU, mbase)                                                          \
  _Pragma("unroll") for (int m_ = 0; m_ < 4; ++m_) {                              \
    a[m_][0] = *(const bf16x8*)&smem[(RBU) + arowU + ((mbase + m_) << 10) + cxu0]; \
    a[m_][1] = *(const bf16x8*)&smem[(RBU) + arowU + ((mbase + m_) << 10) + cxu1]; \
  }
#define RD_B(RBU, breg, nbase)                                                      \
  _Pragma("unroll") for (int n_ = 0; n_ < 2; ++n_) {                                \
    breg[n_][0] = *(const bf16x8*)&smem[(RBU) + browU + ((nbase + n_) << 10) + cxu0]; \
    breg[n_][1] = *(const bf16x8*)&smem[(RBU) + browU + ((nbase + n_) << 10) + cxu1]; \
  }
#define MM(mbase, nbase, breg)                                                     \
  _Pragma("unroll") for (int m_ = 0; m_ < 4; ++m_) _Pragma("unroll") for (int n_ = \
                                                                              0;   \
                                                                          n_ < 2;  \
                                                                          ++n_) {  \
    acc[mbase + m_][nbase + n_] =                                                  \
        MFMA16(a[m_][0], breg[n_][0], acc[mbase + m_][nbase + n_]);                \
    acc[mbase + m_][nbase + n_] =                                                  \
        MFMA16(a[m_][1], breg[n_][1], acc[mbase + m_][nbase + n_]);                \
  }

// One K-tile (BK=64), 4 phases. RBU/WBU = u16 base of read/write LDS buffer.
// PF literal: stages tile(SK) and uses counted vmcnt(4); last tile drains.
#define TILE(RBU, WBU, SK, PF)                                                \
  {                                                                           \
    if (PF) { STAGE_A(WBU, SK) }                                              \
    if (PF) {                                                                 \
      asm volatile("s_waitcnt vmcnt(4)" ::: "memory");                        \
    } else {                                                                  \
      asm volatile("s_waitcnt vmcnt(0)" ::: "memory");                        \
    }                                                                         \
    __builtin_amdgcn_s_barrier();                                             \
    RD_A(RBU, 0);                                                             \
    RD_B(RBU, b0, 0);                                                         \
    asm volatile("s_waitcnt lgkmcnt(0)" ::: "memory");                        \
    __builtin_amdgcn_s_setprio(1);                                            \
    MM(0, 0, b0);                                                             \
    __builtin_amdgcn_s_setprio(0);                                            \
    __builtin_amdgcn_s_barrier();                                             \
    RD_B(RBU, b1, 2);                                                         \
    if (PF) { STAGE_B(WBU, SK) }                                              \
    __builtin_amdgcn_s_barrier();                                             \
    asm volatile("s_waitcnt lgkmcnt(0)" ::: "memory");                        \
    __builtin_amdgcn_s_setprio(1);                                            \
    MM(0, 2, b1);                                                             \
    __builtin_amdgcn_s_setprio(0);                                            \
    __builtin_amdgcn_s_barrier();                                             \
    RD_A(RBU, 4);                                                             \
    __builtin_amdgcn_s_barrier();                                             \
    asm volatile("s_waitcnt lgkmcnt(0)" ::: "memory");                        \
    __builtin_amdgcn_s_setprio(1);                                            \
    MM(4, 2, b1);                                                             \
    __builtin_amdgcn_s_setprio(0);                                            \
    __builtin_amdgcn_s_barrier();                                             \
    __builtin_amdgcn_s_setprio(1);                                            \
    MM(4, 0, b0);                                                             \
    __builtin_amdgcn_s_setprio(0);                                            \
    __builtin_amdgcn_s_barrier();                                             \
  }

__global__ __launch_bounds__(512, 2) void gemm256_qkv(const ushort_t* __restrict__ A,
                                                      const ushort_t* __restrict__ B,
                                                      ushort_t* __restrict__ C) {
  // LDS: 2 bufs x (A 16384 u16 | B 16384 u16) = 128 KiB.
  __shared__ __attribute__((aligned(16))) ushort_t smem[65536];
  const int tid = threadIdx.x;
  const int lane = tid & 63;
  const int w = tid >> 6;
  const int wm = w >> 2, wn = w & 3;

  // XCD-aware swizzle (384 % 8 == 0 -> bijective); row-major tiles: 4 A-panels/XCD.
  const int bid = blockIdx.x;
  const int swz = (bid & 7) * 48 + (bid >> 3);
  const int m0 = (swz / 12) * 256;
  const int n0 = (swz % 12) * 256;

  // staging: thread covers phys 16B chunk c=tid (+512); pre-swizzled source col.
  const int scol = ((tid & 7) ^ ((tid >> 3) & 7)) * 8;
  const ushort_t* gA = A + (size_t)(m0 + (tid >> 3)) * 1024 + scol;
  const ushort_t* gB = B + (size_t)(n0 + (tid >> 3)) * 1024 + scol;

  // read offsets (u16 units): phys = row*64 + ((kk*32 + hi*8) ^ ((lane&7)*8))
  const int lr = lane & 15;
  const int hi = lane >> 4;
  const int arowU = (wm * 128 + lr) * 64;
  const int browU = 16384 + (wn * 64 + lr) * 64;
  const int cxu0 = (hi * 8) ^ ((lane & 7) << 3);
  const int cxu1 = (32 + hi * 8) ^ ((lane & 7) << 3);

  f32x4 acc[8][4] = {};
  bf16x8 a[4][2], b0[2][2], b1[2][2];

  // prologue: stage tile 0 into buf0
  STAGE_A(0, 0)
  STAGE_B(0, 0)

  int sk = 64;
  for (int it = 0; it < 7; ++it) {
    TILE(0, 32768, sk, true) sk += 64;      // even tile: read buf0, stage buf1
    TILE(32768, 0, sk, true) sk += 64;      // odd tile
  }
  TILE(0, 32768, sk, true)                  // t=14 stages tile 15
  TILE(32768, 0, 0, false)                  // t=15: drain, no stage

  const size_t erow = (size_t)(m0 + wm * 128 + hi * 4);
  const int ecol = n0 + wn * 64 + lr;
#pragma unroll
  for (int mf = 0; mf < 8; ++mf)
#pragma unroll
    for (int nf = 0; nf < 4; ++nf)
#pragma unroll
      for (int r = 0; r < 4; ++r)
        C[(erow + mf * 16 + r) * 3072 + ecol + nf * 16] = f2bf(acc[mf][nf][r]);
}

// ---------------- m97-style 128x128 GEMM (kept for the out-projection)
template <bool F32OUT>
__global__ __launch_bounds__(256) void gemm_bt(const ushort_t* __restrict__ A,
                                               const ushort_t* __restrict__ B,
                                               void* __restrict__ C, int M, int N, int K) {
  __shared__ __attribute__((aligned(16))) ushort_t As[128 * 32];
  __shared__ __attribute__((aligned(16))) ushort_t Bs[128 * 32];
  const int tid = threadIdx.x;
  const int lane = tid & 63;
  const int w = tid >> 6;
  const int wr = w >> 1, wc = w & 1;
  const int m0 = blockIdx.x * 128, n0 = blockIdx.y * 128;
  const int lr = lane & 15;
  const int lk = (lane >> 4) << 3;

  f32x4 acc[4][4] = {};

  const int srow = tid >> 2;
  const int scol = (tid & 3) << 3;
  const ushort_t* gA0 = A + (size_t)(m0 + srow) * K + scol;
  const ushort_t* gB0 = B + (size_t)(n0 + srow) * K + scol;
  const size_t rstep = (size_t)64 * K;
  ushort_t* lA0 = &As[(tid & 0xC0) * 8];
  ushort_t* lA1 = lA0 + 2048;
  ushort_t* lB0 = &Bs[(tid & 0xC0) * 8];
  ushort_t* lB1 = lB0 + 2048;

  for (int k0 = 0; k0 < K; k0 += 32) {
    gll16(gA0 + k0, lA0);
    gll16(gA0 + rstep + k0, lA1);
    gll16(gB0 + k0, lB0);
    gll16(gB0 + rstep + k0, lB1);
    __syncthreads();
    bf16x8 a[4], bb[4];
#pragma unroll
    for (int i = 0; i < 4; ++i)
      a[i] = *reinterpret_cast<const bf16x8*>(&As[(wr * 64 + i * 16 + lr) * 32 + lk]);
#pragma unroll
    for (int j = 0; j < 4; ++j)
      bb[j] = *reinterpret_cast<const bf16x8*>(&Bs[(wc * 64 + j * 16 + lr) * 32 + lk]);
#pragma unroll
    for (int i = 0; i < 4; ++i)
#pragma unroll
      for (int j = 0; j < 4; ++j)
        acc[i][j] = __builtin_amdgcn_mfma_f32_16x16x32_bf16(a[i], bb[j], acc[i][j], 0, 0, 0);
    __syncthreads();
  }

  const int orow = m0 + wr * 64 + ((lane >> 4) << 2);
  const int ocol = n0 + wc * 64 + lr;
#pragma unroll
  for (int i = 0; i < 4; ++i)
#pragma unroll
    for (int j = 0; j < 4; ++j)
#pragma unroll
      for (int r = 0; r < 4; ++r) {
        const size_t idx = (size_t)(orow + i * 16 + r) * N + (ocol + j * 16);
        if (F32OUT)
          ((float*)C)[idx] = acc[i][j][r];
        else
          ((ushort_t*)C)[idx] = f2bf(acc[i][j][r]);
      }
}

// Causal flash attention. QKV [8192,3072] bf16 (Q|K|V), Q pre-scaled by 0.125*log2(e).
__global__ __launch_bounds__(256, 2) void attn_fwd(const ushort_t* __restrict__ QKV,
                                                   ushort_t* __restrict__ ctx) {
  const int bid = blockIdx.x;
  const int h = bid & 15;
  const int b = (bid >> 4) & 7;
  const int p = bid >> 7;
  const int tid = threadIdx.x;
  const int lane = tid & 63;
  const int w = tid >> 6;
  const int lr = lane & 15;
  const int lg = lane >> 4;
  const int dk = lg << 3;

  __shared__ __attribute__((aligned(16))) ushort_t Ks[64 * 72];
  __shared__ __attribute__((aligned(16))) uint_t VtDw[64 * 36];
  __shared__ __attribute__((aligned(16))) ushort_t Pl[4][32 * 72];

  const int kkey = tid >> 2, kdg = tid & 3;
  const int vkp = tid & 31, vdg = tid >> 5;
  const ushort_t* kgbase =
      QKV + ((size_t)(b * 1024 + kkey)) * 3072 + 1024 + h * 64 + kdg * 16;
  const ushort_t* vgbase =
      QKV + ((size_t)(b * 1024 + 2 * vkp)) * 3072 + 2048 + h * 64 + vdg * 8;

  const float FMAX2 = 23.083120654223414f;  // 16 * log2(e)

  for (int pi = 0; pi < 2; ++pi) {
    const int qt = pi ? (7 - p) : p;
    const int q0 = qt << 7;
    const int nt = (qt + 1) << 1;
    const int wrow0 = q0 + w * 32;

    bf16x8 qf[2][2];
#pragma unroll
    for (int i = 0; i < 2; ++i) {
      const ushort_t* qp =
          QKV + ((size_t)(b * 1024 + wrow0 + i * 16 + lr)) * 3072 + h * 64 + dk;
      qf[i][0] = *reinterpret_cast<const bf16x8*>(qp);
      qf[i][1] = *reinterpret_cast<const bf16x8*>(qp + 32);
    }

    f32x4 o[2][4] = {};
    float lsum[2] = {0.f, 0.f};

    uint4 rk0 = *reinterpret_cast<const uint4*>(kgbase);
    uint4 rk1 = *reinterpret_cast<const uint4*>(kgbase + 8);
    uint4 rv0 = *reinterpret_cast<const uint4*>(vgbase);
    uint4 rv1 = *reinterpret_cast<const uint4*>(vgbase + 3072);

    for (int t = 0; t < nt; ++t) {
      __syncthreads();
      {
        uint_t* kd = reinterpret_cast<uint_t*>(&Ks[kkey * 72 + kdg * 16]);
        *reinterpret_cast<uint4*>(kd) = rk0;
        *reinterpret_cast<uint4*>(kd + 4) = rk1;
        const ushort_t* e0 = reinterpret_cast<const ushort_t*>(&rv0);
        const ushort_t* e1 = reinterpret_cast<const ushort_t*>(&rv1);
#pragma unroll
        for (int j = 0; j < 8; ++j)
          VtDw[(vdg * 8 + j) * 36 + vkp] = (uint_t)e0[j] | ((uint_t)e1[j] << 16);
      }
      __syncthreads();

      if (t + 1 < nt) {
        const size_t off = (size_t)(t + 1) * 64 * 3072;
        rk0 = *reinterpret_cast<const uint4*>(kgbase + off);
        rk1 = *reinterpret_cast<const uint4*>(kgbase + off + 8);
        rv0 = *reinterpret_cast<const uint4*>(vgbase + off);
        rv1 = *reinterpret_cast<const uint4*>(vgbase + off + 3072);
      }

      const int kb = t << 6;
      if (kb > wrow0 + 31) continue;

      bf16x8 kf0[4], kf1[4];
#pragma unroll
      for (int f = 0; f < 4; ++f) {
        kf0[f] = *reinterpret_cast<const bf16x8*>(&Ks[(f * 16 + lr) * 72 + dk]);
        kf1[f] = *reinterpret_cast<const bf16x8*>(&Ks[(f * 16 + lr) * 72 + 32 + dk]);
      }
      f32x4 s[2][4];
#pragma unroll
      for (int i = 0; i < 2; ++i)
#pragma unroll
        for (int f = 0; f < 4; ++f) {
          f32x4 z = {0.f, 0.f, 0.f, 0.f};
          z = __builtin_amdgcn_mfma_f32_16x16x32_bf16(kf0[f], qf[i][0], z, 0, 0, 0);
          s[i][f] = __builtin_amdgcn_mfma_f32_16x16x32_bf16(kf1[f], qf[i][1], z, 0, 0, 0);
        }

      const bool needmask = (kb + 63 > wrow0);
#pragma unroll
      for (int i = 0; i < 2; ++i) {
        const int qr = wrow0 + i * 16 + lr;
#pragma unroll
        for (int f = 0; f < 4; ++f) {
          const int kbase = kb + f * 16 + (lg << 2);
          float p0 = __builtin_amdgcn_exp2f(s[i][f][0] - FMAX2);
          float p1 = __builtin_amdgcn_exp2f(s[i][f][1] - FMAX2);
          float p2 = __builtin_amdgcn_exp2f(s[i][f][2] - FMAX2);
          float p3 = __builtin_amdgcn_exp2f(s[i][f][3] - FMAX2);
          if (needmask) {
            p0 = (kbase + 0 <= qr) ? p0 : 0.f;
            p1 = (kbase + 1 <= qr) ? p1 : 0.f;
            p2 = (kbase + 2 <= qr) ? p2 : 0.f;
            p3 = (kbase + 3 <= qr) ? p3 : 0.f;
          }
          lsum[i] += (p0 + p1) + (p2 + p3);
          ushort4 pk = {f2bf(p0), f2bf(p1), f2bf(p2), f2bf(p3)};
          *reinterpret_cast<ushort4*>(
              &Pl[w][(i * 16 + lr) * 72 + f * 16 + (lg << 2)]) = pk;
        }
      }

      bf16x8 vb[2][4];
#pragma unroll
      for (int kblk = 0; kblk < 2; ++kblk)
#pragma unroll
        for (int fh = 0; fh < 4; ++fh)
          vb[kblk][fh] = *reinterpret_cast<const bf16x8*>(
              &VtDw[(fh * 16 + lr) * 36 + kblk * 16 + (lg << 2)]);
#pragma unroll
      for (int i = 0; i < 2; ++i)
#pragma unroll
        for (int kblk = 0; kblk < 2; ++kblk) {
          const bf16x8 pa = *reinterpret_cast<const bf16x8*>(
              &Pl[w][(i * 16 + lr) * 72 + kblk * 32 + dk]);
#pragma unroll
          for (int fh = 0; fh < 4; ++fh)
            o[i][fh] = __builtin_amdgcn_mfma_f32_16x16x32_bf16(pa, vb[kblk][fh],
                                                               o[i][fh], 0, 0, 0);
        }
    }

#pragma unroll
    for (int i = 0; i < 2; ++i) {
      float ls = lsum[i];
      ls += __shfl_xor(ls, 16);
      ls += __shfl_xor(ls, 32);
      const float linv = 1.0f / ls;
      const size_t crow = (size_t)(b * 1024 + wrow0 + i * 16 + (lg << 2));
#pragma unroll
      for (int r = 0; r < 4; ++r) {
        const float li = __shfl(linv, (lg << 2) + r);
#pragma unroll
        for (int fh = 0; fh < 4; ++fh)
          ctx[(crow + r) * 1024 + h * 64 + fh * 16 + lr] = f2bf(o[i][fh][r] * li);
      }
    }
  }
}

extern "C" void kernel_launch(void* const* d_in, const int* in_sizes, int n_in,
                              void* d_out, int out_size, void* d_ws, size_t ws_size,
                              hipStream_t stream) {
  const float* x = (const float*)d_in[0];
  const float* Wk = (const float*)d_in[1];
  const float* Wq = (const float*)d_in[2];
  const float* Wv = (const float*)d_in[3];
  const float* Wo = (const float*)d_in[4];

  char* ws = (char*)d_ws;
  ushort_t* xb = (ushort_t*)ws;                  // [8192,1024] bf16 (reused as ctx)
  ushort_t* Wc = (ushort_t*)(ws + (16u << 20));  // Wq*0.125*log2e | Wk | Wv | Wo
  ushort_t* Wob = Wc + 3u * 1024 * 1024;
  ushort_t* QKV = (ushort_t*)(ws + (24u << 20));  // [8192,3072] bf16
  ushort_t* ctx = xb;

  cast_bf16<<<2048, 256, 0, stream>>>(x, xb, (8192 * 1024) / 4, 1.0f);
  cast_w4<<<4096, 256, 0, stream>>>(Wq, Wk, Wv, Wo, Wc, 0.125f * 1.4426950408889634f);

  gemm256_qkv<<<384, 512, 0, stream>>>(xb, Wc, QKV);

  attn_fwd<<<512, 256, 0, stream>>>(QKV, ctx);

  dim3 g2(64, 8);
  gemm_bt<true><<<g2, 256, 0, stream>>>(ctx, Wob, (float*)d_out, 8192, 1024, 1024);
}

// Round 5
// 146.846 us; speedup vs baseline: 2.1416x; 1.0038x over previous
//
#include <hip/hip_runtime.h>
#include <stdint.h>

typedef __bf16 bf16x8 __attribute__((ext_vector_type(8)));
typedef float f32x4 __attribute__((ext_vector_type(4)));
typedef unsigned short ushort_t;
typedef unsigned int uint_t;

__device__ inline ushort_t f2bf(float f) {
  uint_t u = __builtin_bit_cast(uint_t, f);
  u = (u + 0x7FFFu + ((u >> 16) & 1u)) >> 16;
  return (ushort_t)u;
}

// async global->LDS, 16B per lane. LDS dest must be wave-uniform base; HW adds lane*16.
__device__ inline void gll16(const void* g, void* l) {
  __builtin_amdgcn_global_load_lds(
      (__attribute__((address_space(1))) void*)(uintptr_t)g,
      (__attribute__((address_space(3))) void*)(uint32_t)(uintptr_t)l,
      16, 0, 0);
}

__global__ void cast_bf16(const float* __restrict__ in, ushort_t* __restrict__ out,
                          int n4, float scale) {
  int i = blockIdx.x * blockDim.x + threadIdx.x;
  int st = gridDim.x * blockDim.x;
  for (; i < n4; i += st) {
    float4 v = reinterpret_cast<const float4*>(in)[i];
    ushort4 o;
    o.x = f2bf(v.x * scale);
    o.y = f2bf(v.y * scale);
    o.z = f2bf(v.z * scale);
    o.w = f2bf(v.w * scale);
    reinterpret_cast<ushort4*>(out)[i] = o;
  }
}

// All 4 weight matrices in one launch; out = Wq*s | Wk | Wv | Wo contiguous.
__global__ void cast_w4(const float* __restrict__ w0, const float* __restrict__ w1,
                        const float* __restrict__ w2, const float* __restrict__ w3,
                        ushort_t* __restrict__ out, float s0) {
  const int i = blockIdx.x * 256 + threadIdx.x;
  const int which = i >> 18;
  const float* src = which == 0 ? w0 : which == 1 ? w1 : which == 2 ? w2 : w3;
  const float sc = which == 0 ? s0 : 1.0f;
  float4 v = reinterpret_cast<const float4*>(src)[i & 0x3FFFF];
  ushort4 o;
  o.x = f2bf(v.x * sc);
  o.y = f2bf(v.y * sc);
  o.z = f2bf(v.z * sc);
  o.w = f2bf(v.w * sc);
  reinterpret_cast<ushort4*>(out)[i] = o;
}

// ---------------- 8-phase 256x256 GEMM: C[8192,3072] = A[8192,1024] * B[3072,1024]^T
#define MFMA16(A_, B_, C_) __builtin_amdgcn_mfma_f32_16x16x32_bf16(A_, B_, C_, 0, 0, 0)

// stage one operand tile half-pair: 4 gll16 (rows +0,+64,+128,+192), LDS linear.
#define STAGE_A(WBU, SK)                                              \
  gll16(gA + (SK), &smem[(WBU) + (w << 9)]);                          \
  gll16(gA + 65536 + (SK), &smem[(WBU) + 4096 + (w << 9)]);           \
  gll16(gA + 131072 + (SK), &smem[(WBU) + 8192 + (w << 9)]);          \
  gll16(gA + 196608 + (SK), &smem[(WBU) + 12288 + (w << 9)]);
#define STAGE_B(WBU, SK)                                              \
  gll16(gB + (SK), &smem[(WBU) + 16384 + (w << 9)]);                  \
  gll16(gB + 65536 + (SK), &smem[(WBU) + 20480 + (w << 9)]);          \
  gll16(gB + 131072 + (SK), &smem[(WBU) + 24576 + (w << 9)]);         \
  gll16(gB + 196608 + (SK), &smem[(WBU) + 28672 + (w << 9)]);

#define RD_A(RBU, mbase)                                                          \
  _Pragma("unroll") for (int m_ = 0; m_ < 4; ++m_) {                              \
    a[m_][0] = *(const bf16x8*)&smem[(RBU) + arowU + ((mbase + m_) << 10) + cxu0]; \
    a[m_][1] = *(const bf16x8*)&smem[(RBU) + arowU + ((mbase + m_) << 10) + cxu1]; \
  }
#define RD_B(RBU, breg, nbase)                                                      \
  _Pragma("unroll") for (int n_ = 0; n_ < 2; ++n_) {                                \
    breg[n_][0] = *(const bf16x8*)&smem[(RBU) + browU + ((nbase + n_) << 10) + cxu0]; \
    breg[n_][1] = *(const bf16x8*)&smem[(RBU) + browU + ((nbase + n_) << 10) + cxu1]; \
  }
#define MM(mbase, nbase, breg)                                                     \
  _Pragma("unroll") for (int m_ = 0; m_ < 4; ++m_) _Pragma("unroll") for (int n_ = \
                                                                              0;   \
                                                                          n_ < 2;  \
                                                                          ++n_) {  \
    acc[mbase + m_][nbase + n_] =                                                  \
        MFMA16(a[m_][0], breg[n_][0], acc[mbase + m_][nbase + n_]);                \
    acc[mbase + m_][nbase + n_] =                                                  \
        MFMA16(a[m_][1], breg[n_][1], acc[mbase + m_][nbase + n_]);                \
  }

// One K-tile (BK=64), 4 phases. RBU/WBU = u16 base of read/write LDS buffer.
// PF literal: stages tile(SK) and uses counted vmcnt(4); last tile drains.
#define TILE(RBU, WBU, SK, PF)                                                \
  {                                                                           \
    if (PF) { STAGE_A(WBU, SK) }                                              \
    if (PF) {                                                                 \
      asm volatile("s_waitcnt vmcnt(4)" ::: "memory");                        \
    } else {                                                                  \
      asm volatile("s_waitcnt vmcnt(0)" ::: "memory");                        \
    }                                                                         \
    __builtin_amdgcn_s_barrier();                                             \
    RD_A(RBU, 0);                                                             \
    RD_B(RBU, b0, 0);                                                         \
    asm volatile("s_waitcnt lgkmcnt(0)" ::: "memory");                        \
    __builtin_amdgcn_s_setprio(1);                                            \
    MM(0, 0, b0);                                                             \
    __builtin_amdgcn_s_setprio(0);                                            \
    __builtin_amdgcn_s_barrier();                                             \
    RD_B(RBU, b1, 2);                                                         \
    if (PF) { STAGE_B(WBU, SK) }                                              \
    __builtin_amdgcn_s_barrier();                                             \
    asm volatile("s_waitcnt lgkmcnt(0)" ::: "memory");                        \
    __builtin_amdgcn_s_setprio(1);                                            \
    MM(0, 2, b1);                                                             \
    __builtin_amdgcn_s_setprio(0);                                            \
    __builtin_amdgcn_s_barrier();                                             \
    RD_A(RBU, 4);                                                             \
    __builtin_amdgcn_s_barrier();                                             \
    asm volatile("s_waitcnt lgkmcnt(0)" ::: "memory");                        \
    __builtin_amdgcn_s_setprio(1);                                            \
    MM(4, 2, b1);                                                             \
    __builtin_amdgcn_s_setprio(0);                                            \
    __builtin_amdgcn_s_barrier();                                             \
    __builtin_amdgcn_s_setprio(1);                                            \
    MM(4, 0, b0);                                                             \
    __builtin_amdgcn_s_setprio(0);                                            \
    __builtin_amdgcn_s_barrier();                                             \
  }

__global__ __launch_bounds__(512, 2) void gemm256_qkv(const ushort_t* __restrict__ A,
                                                      const ushort_t* __restrict__ B,
                                                      ushort_t* __restrict__ C) {
  // LDS: 2 bufs x (A 16384 u16 | B 16384 u16) = 128 KiB.
  __shared__ __attribute__((aligned(16))) ushort_t smem[65536];
  const int tid = threadIdx.x;
  const int lane = tid & 63;
  const int w = tid >> 6;
  const int wm = w >> 2, wn = w & 3;

  // XCD-aware swizzle (384 % 8 == 0 -> bijective); row-major tiles: 4 A-panels/XCD.
  const int bid = blockIdx.x;
  const int swz = (bid & 7) * 48 + (bid >> 3);
  const int m0 = (swz / 12) * 256;
  const int n0 = (swz % 12) * 256;

  // staging: thread covers phys 16B chunk c=tid (+512); pre-swizzled source col.
  const int scol = ((tid & 7) ^ ((tid >> 3) & 7)) * 8;
  const ushort_t* gA = A + (size_t)(m0 + (tid >> 3)) * 1024 + scol;
  const ushort_t* gB = B + (size_t)(n0 + (tid >> 3)) * 1024 + scol;

  // read offsets (u16 units): phys = row*64 + ((kk*32 + hi*8) ^ ((lane&7)*8))
  const int lr = lane & 15;
  const int hi = lane >> 4;
  const int arowU = (wm * 128 + lr) * 64;
  const int browU = 16384 + (wn * 64 + lr) * 64;
  const int cxu0 = (hi * 8) ^ ((lane & 7) << 3);
  const int cxu1 = (32 + hi * 8) ^ ((lane & 7) << 3);

  f32x4 acc[8][4] = {};
  bf16x8 a[4][2], b0[2][2], b1[2][2];

  // prologue: stage tile 0 into buf0
  STAGE_A(0, 0)
  STAGE_B(0, 0)

  int sk = 64;
  for (int it = 0; it < 7; ++it) {
    TILE(0, 32768, sk, true) sk += 64;      // even tile: read buf0, stage buf1
    TILE(32768, 0, sk, true) sk += 64;      // odd tile
  }
  TILE(0, 32768, sk, true)                  // t=14 stages tile 15
  TILE(32768, 0, 0, false)                  // t=15: drain, no stage

  const size_t erow = (size_t)(m0 + wm * 128 + hi * 4);
  const int ecol = n0 + wn * 64 + lr;
#pragma unroll
  for (int mf = 0; mf < 8; ++mf)
#pragma unroll
    for (int nf = 0; nf < 4; ++nf)
#pragma unroll
      for (int r = 0; r < 4; ++r)
        C[(erow + mf * 16 + r) * 3072 + ecol + nf * 16] = f2bf(acc[mf][nf][r]);
}

// ---------------- m97-style 128x128 GEMM (kept for the out-projection)
template <bool F32OUT>
__global__ __launch_bounds__(256) void gemm_bt(const ushort_t* __restrict__ A,
                                               const ushort_t* __restrict__ B,
                                               void* __restrict__ C, int M, int N, int K) {
  __shared__ __attribute__((aligned(16))) ushort_t As[128 * 32];
  __shared__ __attribute__((aligned(16))) ushort_t Bs[128 * 32];
  const int tid = threadIdx.x;
  const int lane = tid & 63;
  const int w = tid >> 6;
  const int wr = w >> 1, wc = w & 1;
  const int m0 = blockIdx.x * 128, n0 = blockIdx.y * 128;
  const int lr = lane & 15;
  const int lk = (lane >> 4) << 3;

  f32x4 acc[4][4] = {};

  const int srow = tid >> 2;
  const int scol = (tid & 3) << 3;
  const ushort_t* gA0 = A + (size_t)(m0 + srow) * K + scol;
  const ushort_t* gB0 = B + (size_t)(n0 + srow) * K + scol;
  const size_t rstep = (size_t)64 * K;
  ushort_t* lA0 = &As[(tid & 0xC0) * 8];
  ushort_t* lA1 = lA0 + 2048;
  ushort_t* lB0 = &Bs[(tid & 0xC0) * 8];
  ushort_t* lB1 = lB0 + 2048;

  for (int k0 = 0; k0 < K; k0 += 32) {
    gll16(gA0 + k0, lA0);
    gll16(gA0 + rstep + k0, lA1);
    gll16(gB0 + k0, lB0);
    gll16(gB0 + rstep + k0, lB1);
    __syncthreads();
    bf16x8 a[4], bb[4];
#pragma unroll
    for (int i = 0; i < 4; ++i)
      a[i] = *reinterpret_cast<const bf16x8*>(&As[(wr * 64 + i * 16 + lr) * 32 + lk]);
#pragma unroll
    for (int j = 0; j < 4; ++j)
      bb[j] = *reinterpret_cast<const bf16x8*>(&Bs[(wc * 64 + j * 16 + lr) * 32 + lk]);
#pragma unroll
    for (int i = 0; i < 4; ++i)
#pragma unroll
      for (int j = 0; j < 4; ++j)
        acc[i][j] = __builtin_amdgcn_mfma_f32_16x16x32_bf16(a[i], bb[j], acc[i][j], 0, 0, 0);
    __syncthreads();
  }

  const int orow = m0 + wr * 64 + ((lane >> 4) << 2);
  const int ocol = n0 + wc * 64 + lr;
#pragma unroll
  for (int i = 0; i < 4; ++i)
#pragma unroll
    for (int j = 0; j < 4; ++j)
#pragma unroll
      for (int r = 0; r < 4; ++r) {
        const size_t idx = (size_t)(orow + i * 16 + r) * N + (ocol + j * 16);
        if (F32OUT)
          ((float*)C)[idx] = acc[i][j][r];
        else
          ((ushort_t*)C)[idx] = f2bf(acc[i][j][r]);
      }
}

// Causal flash attention. QKV [8192,3072] bf16 (Q|K|V), Q pre-scaled by 0.125*log2(e).
__global__ __launch_bounds__(256, 2) void attn_fwd(const ushort_t* __restrict__ QKV,
                                                   ushort_t* __restrict__ ctx) {
  const int bid = blockIdx.x;
  const int h = bid & 15;
  const int b = (bid >> 4) & 7;
  const int p = bid >> 7;
  const int tid = threadIdx.x;
  const int lane = tid & 63;
  const int w = tid >> 6;
  const int lr = lane & 15;
  const int lg = lane >> 4;
  const int dk = lg << 3;

  __shared__ __attribute__((aligned(16))) ushort_t Ks[64 * 72];
  __shared__ __attribute__((aligned(16))) uint_t VtDw[64 * 36];
  __shared__ __attribute__((aligned(16))) ushort_t Pl[4][32 * 72];

  const int kkey = tid >> 2, kdg = tid & 3;
  const int vkp = tid & 31, vdg = tid >> 5;
  const ushort_t* kgbase =
      QKV + ((size_t)(b * 1024 + kkey)) * 3072 + 1024 + h * 64 + kdg * 16;
  const ushort_t* vgbase =
      QKV + ((size_t)(b * 1024 + 2 * vkp)) * 3072 + 2048 + h * 64 + vdg * 8;

  const float FMAX2 = 23.083120654223414f;  // 16 * log2(e)

  for (int pi = 0; pi < 2; ++pi) {
    const int qt = pi ? (7 - p) : p;
    const int q0 = qt << 7;
    const int nt = (qt + 1) << 1;
    const int wrow0 = q0 + w * 32;

    bf16x8 qf[2][2];
#pragma unroll
    for (int i = 0; i < 2; ++i) {
      const ushort_t* qp =
          QKV + ((size_t)(b * 1024 + wrow0 + i * 16 + lr)) * 3072 + h * 64 + dk;
      qf[i][0] = *reinterpret_cast<const bf16x8*>(qp);
      qf[i][1] = *reinterpret_cast<const bf16x8*>(qp + 32);
    }

    f32x4 o[2][4] = {};
    float lsum[2] = {0.f, 0.f};

    uint4 rk0 = *reinterpret_cast<const uint4*>(kgbase);
    uint4 rk1 = *reinterpret_cast<const uint4*>(kgbase + 8);
    uint4 rv0 = *reinterpret_cast<const uint4*>(vgbase);
    uint4 rv1 = *reinterpret_cast<const uint4*>(vgbase + 3072);

    for (int t = 0; t < nt; ++t) {
      __syncthreads();
      {
        uint_t* kd = reinterpret_cast<uint_t*>(&Ks[kkey * 72 + kdg * 16]);
        *reinterpret_cast<uint4*>(kd) = rk0;
        *reinterpret_cast<uint4*>(kd + 4) = rk1;
        const ushort_t* e0 = reinterpret_cast<const ushort_t*>(&rv0);
        const ushort_t* e1 = reinterpret_cast<const ushort_t*>(&rv1);
#pragma unroll
        for (int j = 0; j < 8; ++j)
          VtDw[(vdg * 8 + j) * 36 + vkp] = (uint_t)e0[j] | ((uint_t)e1[j] << 16);
      }
      __syncthreads();

      if (t + 1 < nt) {
        const size_t off = (size_t)(t + 1) * 64 * 3072;
        rk0 = *reinterpret_cast<const uint4*>(kgbase + off);
        rk1 = *reinterpret_cast<const uint4*>(kgbase + off + 8);
        rv0 = *reinterpret_cast<const uint4*>(vgbase + off);
        rv1 = *reinterpret_cast<const uint4*>(vgbase + off + 3072);
      }

      const int kb = t << 6;
      if (kb > wrow0 + 31) continue;

      bf16x8 kf0[4], kf1[4];
#pragma unroll
      for (int f = 0; f < 4; ++f) {
        kf0[f] = *reinterpret_cast<const bf16x8*>(&Ks[(f * 16 + lr) * 72 + dk]);
        kf1[f] = *reinterpret_cast<const bf16x8*>(&Ks[(f * 16 + lr) * 72 + 32 + dk]);
      }
      f32x4 s[2][4];
#pragma unroll
      for (int i = 0; i < 2; ++i)
#pragma unroll
        for (int f = 0; f < 4; ++f) {
          f32x4 z = {0.f, 0.f, 0.f, 0.f};
          z = __builtin_amdgcn_mfma_f32_16x16x32_bf16(kf0[f], qf[i][0], z, 0, 0, 0);
          s[i][f] = __builtin_amdgcn_mfma_f32_16x16x32_bf16(kf1[f], qf[i][1], z, 0, 0, 0);
        }

      const bool needmask = (kb + 63 > wrow0);
#pragma unroll
      for (int i = 0; i < 2; ++i) {
        const int qr = wrow0 + i * 16 + lr;
#pragma unroll
        for (int f = 0; f < 4; ++f) {
          const int kbase = kb + f * 16 + (lg << 2);
          float p0 = __builtin_amdgcn_exp2f(s[i][f][0] - FMAX2);
          float p1 = __builtin_amdgcn_exp2f(s[i][f][1] - FMAX2);
          float p2 = __builtin_amdgcn_exp2f(s[i][f][2] - FMAX2);
          float p3 = __builtin_amdgcn_exp2f(s[i][f][3] - FMAX2);
          if (needmask) {
            p0 = (kbase + 0 <= qr) ? p0 : 0.f;
            p1 = (kbase + 1 <= qr) ? p1 : 0.f;
            p2 = (kbase + 2 <= qr) ? p2 : 0.f;
            p3 = (kbase + 3 <= qr) ? p3 : 0.f;
          }
          lsum[i] += (p0 + p1) + (p2 + p3);
          ushort4 pk = {f2bf(p0), f2bf(p1), f2bf(p2), f2bf(p3)};
          *reinterpret_cast<ushort4*>(
              &Pl[w][(i * 16 + lr) * 72 + f * 16 + (lg << 2)]) = pk;
        }
      }

      bf16x8 vb[2][4];
#pragma unroll
      for (int kblk = 0; kblk < 2; ++kblk)
#pragma unroll
        for (int fh = 0; fh < 4; ++fh)
          vb[kblk][fh] = *reinterpret_cast<const bf16x8*>(
              &VtDw[(fh * 16 + lr) * 36 + kblk * 16 + (lg << 2)]);
#pragma unroll
      for (int i = 0; i < 2; ++i)
#pragma unroll
        for (int kblk = 0; kblk < 2; ++kblk) {
          const bf16x8 pa = *reinterpret_cast<const bf16x8*>(
              &Pl[w][(i * 16 + lr) * 72 + kblk * 32 + dk]);
#pragma unroll
          for (int fh = 0; fh < 4; ++fh)
            o[i][fh] = __builtin_amdgcn_mfma_f32_16x16x32_bf16(pa, vb[kblk][fh],
                                                               o[i][fh], 0, 0, 0);
        }
    }

#pragma unroll
    for (int i = 0; i < 2; ++i) {
      float ls = lsum[i];
      ls += __shfl_xor(ls, 16);
      ls += __shfl_xor(ls, 32);
      const float linv = 1.0f / ls;
      const size_t crow = (size_t)(b * 1024 + wrow0 + i * 16 + (lg << 2));
#pragma unroll
      for (int r = 0; r < 4; ++r) {
        const float li = __shfl(linv, (lg << 2) + r);
#pragma unroll
        for (int fh = 0; fh < 4; ++fh)
          ctx[(crow + r) * 1024 + h * 64 + fh * 16 + lr] = f2bf(o[i][fh][r] * li);
      }
    }
  }
}

extern "C" void kernel_launch(void* const* d_in, const int* in_sizes, int n_in,
                              void* d_out, int out_size, void* d_ws, size_t ws_size,
                              hipStream_t stream) {
  const float* x = (const float*)d_in[0];
  const float* Wk = (const float*)d_in[1];
  const float* Wq = (const float*)d_in[2];
  const float* Wv = (const float*)d_in[3];
  const float* Wo = (const float*)d_in[4];

  char* ws = (char*)d_ws;
  ushort_t* xb = (ushort_t*)ws;                  // [8192,1024] bf16 (reused as ctx)
  ushort_t* Wc = (ushort_t*)(ws + (16u << 20));  // Wq*0.125*log2e | Wk | Wv | Wo
  ushort_t* Wob = Wc + 3u * 1024 * 1024;
  ushort_t* QKV = (ushort_t*)(ws + (24u << 20));  // [8192,3072] bf16
  ushort_t* ctx = xb;

  cast_bf16<<<2048, 256, 0, stream>>>(x, xb, (8192 * 1024) / 4, 1.0f);
  cast_w4<<<4096, 256, 0, stream>>>(Wq, Wk, Wv, Wo, Wc, 0.125f * 1.4426950408889634f);

  gemm256_qkv<<<384, 512, 0, stream>>>(xb, Wc, QKV);

  attn_fwd<<<512, 256, 0, stream>>>(QKV, ctx);

  dim3 g2(64, 8);
  gemm_bt<true><<<g2, 256, 0, stream>>>(ctx, Wob, (float*)d_out, 8192, 1024, 1024);
}